// Round 1
// baseline (215.742 us; speedup 1.0000x reference)
//
#include <hip/hip_runtime.h>

#define BB 8
#define CC_TOT 64
#define HH 128
#define WW 256
#define DD 64
#define CCHUNK 16          // channels staged per LDS chunk
#define RPAD 64            // zero pad on the left of the right-row (negative shifts)
#define RW (WW + RPAD)     // 320

// volume[b,d,h,w] = (1/64) * sum_c L[b,c,h,w] * R[b,c,h,w-d]   (0 when w<d)
__global__ __launch_bounds__(256, 4)
void corr_volume_kernel(const float* __restrict__ left,
                        const float* __restrict__ right,
                        float* __restrict__ out) {
    __shared__ alignas(16) float ldsL[CCHUNK][WW];   // 16 KiB
    __shared__ alignas(16) float ldsR[CCHUNK][RW];   // 20 KiB

    const int tid = threadIdx.x;
    const int bh  = blockIdx.x;
    const int b   = bh >> 7;     // / 128
    const int h   = bh & 127;

    // Zero the pad region of ldsR: CCHUNK*RPAD = 1024 floats, 4 per thread.
    #pragma unroll
    for (int i = 0; i < 4; ++i) {
        int f  = i * 256 + tid;      // 0..1023
        int cc = f >> 6;
        int p  = f & 63;
        ldsR[cc][p] = 0.0f;
    }

    const int tw = tid & 63;     // w-group within wave (lane)
    const int td = tid >> 6;     // d-group (wave index)
    const int w0 = tw * 4;       // this thread's 4 w's: w0..w0+3
    const int d0 = td * 16;      // this thread's 16 d's: d0..d0+15

    float acc[16][4];
    #pragma unroll
    for (int dd = 0; dd < 16; ++dd)
        #pragma unroll
        for (int i = 0; i < 4; ++i)
            acc[dd][i] = 0.0f;

    const size_t chanStride = (size_t)HH * WW;                  // 32768
    const size_t rowBase    = (size_t)b * CC_TOT * chanStride + (size_t)h * WW;

    for (int c0 = 0; c0 < CC_TOT; c0 += CCHUNK) {
        __syncthreads();   // protect previous chunk's LDS reads (and pad init)
        // Stage CCHUNK channel-rows of left & right (fully coalesced float4).
        #pragma unroll
        for (int i = 0; i < 4; ++i) {
            int f  = i * 256 + tid;  // float4 index within chunk, 0..1023
            int cc = f >> 6;         // 64 float4 per channel row
            int w4 = f & 63;
            const float* lp = left  + rowBase + (size_t)(c0 + cc) * chanStride;
            const float* rp = right + rowBase + (size_t)(c0 + cc) * chanStride;
            float4 lv = ((const float4*)lp)[w4];
            float4 rv = ((const float4*)rp)[w4];
            *(float4*)&ldsL[cc][w4 * 4]        = lv;
            *(float4*)&ldsR[cc][RPAD + w4 * 4] = rv;
        }
        __syncthreads();

        for (int cc = 0; cc < CCHUNK; ++cc) {
            float4 Lv = *(const float4*)&ldsL[cc][w0];
            // Right sliding window: s = w - d, padded index s+RPAD.
            // a0 = w0 - d0 + 48 is float4-aligned (w0%4==0, d0%16==0) and >= 0.
            const int a0 = w0 - d0 + 48;
            float r[20];
            #pragma unroll
            for (int k = 0; k < 5; ++k) {
                float4 rv = *(const float4*)&ldsR[cc][a0 + 4 * k];
                r[4 * k + 0] = rv.x;
                r[4 * k + 1] = rv.y;
                r[4 * k + 2] = rv.z;
                r[4 * k + 3] = rv.w;
            }
            // idx = (w0+i - (d0+dd) + RPAD) - a0 = 16 - dd + i  ∈ [1, 19]
            const float* Ls = (const float*)&Lv;
            #pragma unroll
            for (int dd = 0; dd < 16; ++dd) {
                #pragma unroll
                for (int i = 0; i < 4; ++i) {
                    acc[dd][i] = fmaf(Ls[i], r[16 - dd + i], acc[dd][i]);
                }
            }
        }
    }

    // Epilogue: out[b][d][h][w], scale by 1/64. Invalid (w<d) entries hit the
    // zero pad during accumulation and are exactly 0 already.
    const float scale = 1.0f / 64.0f;
    #pragma unroll
    for (int dd = 0; dd < 16; ++dd) {
        int d = d0 + dd;
        float4 o;
        o.x = acc[dd][0] * scale;
        o.y = acc[dd][1] * scale;
        o.z = acc[dd][2] * scale;
        o.w = acc[dd][3] * scale;
        size_t oidx = (((size_t)b * DD + d) * HH + h) * (size_t)WW + w0;
        *(float4*)(out + oidx) = o;
    }
}

extern "C" void kernel_launch(void* const* d_in, const int* in_sizes, int n_in,
                              void* d_out, int out_size, void* d_ws, size_t ws_size,
                              hipStream_t stream) {
    const float* left  = (const float*)d_in[0];
    const float* right = (const float*)d_in[1];
    // d_in[2] = max_disp (scalar on device); fixed at 64 per problem setup.
    float* out = (float*)d_out;

    dim3 grid(BB * HH);   // 1024 blocks, one per (b, h) row
    dim3 block(256);
    corr_volume_kernel<<<grid, block, 0, stream>>>(left, right, out);
}